// Round 1
// baseline (45.006 us; speedup 1.0000x reference)
//
#include <hip/hip_runtime.h>

#define VOCAB 100000
#define DIM 128
#define BATCH 65536
#define NEG 5

#define BLOCKS 1024
#define TPB 256
// 16 lanes per element -> 16 groups per block
#define GRPS_PER_BLK (TPB / 16)

__device__ __forceinline__ float log_sigmoid(float x) {
    // numerically stable: min(x,0) - log1p(exp(-|x|))
    return fminf(x, 0.0f) - log1pf(expf(-fabsf(x)));
}

__device__ __forceinline__ float dot4(float4 a, float4 b) {
    return a.x * b.x + a.y * b.y + a.z * b.z + a.w * b.w;
}

__global__ __launch_bounds__(TPB) void g2v_partial(
    const float* __restrict__ W_in, const float* __restrict__ W_ctx,
    const int* __restrict__ input_word, const int* __restrict__ context_word,
    const int* __restrict__ neg_idx, float* __restrict__ block_sums)
{
    const int lane16 = threadIdx.x & 15;
    const int grp_in_blk = threadIdx.x >> 4;
    const int grp = blockIdx.x * GRPS_PER_BLK + grp_in_blk;
    const int ngrp = gridDim.x * GRPS_PER_BLK;

    const float4* __restrict__ W_in4 = (const float4*)W_in;
    const float4* __restrict__ W_ctx4 = (const float4*)W_ctx;

    float gsum = 0.0f;

    for (int b = grp; b < BATCH; b += ngrp) {
        const int iw = input_word[b];
        const int cw = context_word[b];

        // row = 128 floats = 32 float4; lane16 covers 2 float4 (stride 16)
        const float4* ri = W_in4 + iw * 32 + lane16;
        const float4 ei0 = ri[0];
        const float4 ei1 = ri[16];

        const float4* rc = W_ctx4 + cw * 32 + lane16;
        const float4 ec0 = rc[0];
        const float4 ec1 = rc[16];

        float pos = dot4(ei0, ec0) + dot4(ei1, ec1);

        float nd[NEG];
        #pragma unroll
        for (int k = 0; k < NEG; ++k) {
            const int nw = neg_idx[b * NEG + k];
            const float4* rn = W_in4 + nw * 32 + lane16;
            const float4 en0 = rn[0];
            const float4 en1 = rn[16];
            nd[k] = dot4(en0, ei0) + dot4(en1, ei1);
        }

        // butterfly reduce within each 16-lane group (masks 1,2,4,8)
        #pragma unroll
        for (int m = 1; m <= 8; m <<= 1) {
            pos += __shfl_xor(pos, m);
            #pragma unroll
            for (int k = 0; k < NEG; ++k) nd[k] += __shfl_xor(nd[k], m);
        }

        if (lane16 == 0) {
            float loss = log_sigmoid(pos);
            #pragma unroll
            for (int k = 0; k < NEG; ++k) loss += log_sigmoid(-nd[k]);
            gsum += loss;
        }
    }

    __shared__ float s[GRPS_PER_BLK];
    if (lane16 == 0) s[grp_in_blk] = gsum;
    __syncthreads();
    if (threadIdx.x == 0) {
        float t = 0.0f;
        #pragma unroll
        for (int i = 0; i < GRPS_PER_BLK; ++i) t += s[i];
        block_sums[blockIdx.x] = t;
    }
}

__global__ __launch_bounds__(256) void g2v_final(
    const float* __restrict__ block_sums, int n, float* __restrict__ out)
{
    __shared__ float s[256];
    float t = 0.0f;
    for (int i = threadIdx.x; i < n; i += 256) t += block_sums[i];
    s[threadIdx.x] = t;
    __syncthreads();
    for (int w = 128; w > 0; w >>= 1) {
        if (threadIdx.x < w) s[threadIdx.x] += s[threadIdx.x + w];
        __syncthreads();
    }
    if (threadIdx.x == 0) out[0] = -s[0] / (float)BATCH;
}

extern "C" void kernel_launch(void* const* d_in, const int* in_sizes, int n_in,
                              void* d_out, int out_size, void* d_ws, size_t ws_size,
                              hipStream_t stream) {
    const float* W_in        = (const float*)d_in[0];
    const float* W_ctx       = (const float*)d_in[1];
    const int*   input_word  = (const int*)d_in[2];
    const int*   context_word= (const int*)d_in[3];
    const int*   neg_idx     = (const int*)d_in[4];

    float* block_sums = (float*)d_ws;   // BLOCKS floats
    float* out        = (float*)d_out;

    g2v_partial<<<BLOCKS, TPB, 0, stream>>>(W_in, W_ctx, input_word,
                                            context_word, neg_idx, block_sums);
    g2v_final<<<1, 256, 0, stream>>>(block_sums, BLOCKS, out);
}